// Round 3
// baseline (5076.369 us; speedup 1.0000x reference)
//
#include <hip/hip_runtime.h>
#include <hip/hip_bf16.h>

#define EPS  1e-5f
#define CNTF 409600.0f            // N*T*V
#define XDP_ELEMS 6553600         // 16384 * 400 per layer
#define Z_ELEMS   32768000        // 16384 * 2000

__device__ __forceinline__ float wave_sum(float v) {
#pragma unroll
    for (int off = 32; off > 0; off >>= 1)
        v += __shfl_down(v, off, 64);
    return v;
}

__device__ __forceinline__ float bfu(unsigned int u16) {
    union { unsigned int i; float f; } x;
    x.i = u16 << 16;
    return x.f;
}

// ---- K1: conv_down all 3 layers (no bias - cancels in BN), raw bf16 xd + stats
__global__ __launch_bounds__(256) void k_down3(
    const float* __restrict__ x, const float* __restrict__ Wd,
    __hip_bfloat16* __restrict__ xdp, float* __restrict__ st /*96*/)
{
    __shared__ float Wt[64][48];
    __shared__ float bins[96];
    const int tid = threadIdx.x;
    for (int i = tid; i < 3072; i += 256) {
        int c = i / 48, k = i - c * 48;
        int l = k / 16, o = k - l * 16;
        Wt[c][k] = Wd[l * 1024 + o * 64 + c];
    }
    if (tid < 96) bins[tid] = 0.f;
    __syncthreads();

    const int base = (blockIdx.x * 256 + tid) * 2;
    const int n = base / 3200, pb = base - n * 3200;
    const float* xb = x + n * 204800 + pb;
    float acc[2][48];
#pragma unroll
    for (int k = 0; k < 48; k++) { acc[0][k] = 0.f; acc[1][k] = 0.f; }
    for (int c = 0; c < 64; c++) {
        float2 xv = *(const float2*)&xb[c * 3200];
#pragma unroll
        for (int k = 0; k < 48; k++) {
            float wv = Wt[c][k];
            acc[0][k] += wv * xv.x;
            acc[1][k] += wv * xv.y;
        }
    }
#pragma unroll
    for (int j = 0; j < 2; j++) {
        int p = base + j;
        int nt = p / 25, u = p - nt * 25;
#pragma unroll
        for (int l = 0; l < 3; l++)
#pragma unroll
            for (int o = 0; o < 16; o++)
                xdp[(size_t)l * XDP_ELEMS + (size_t)nt * 400 + o * 25 + u] =
                    __float2bfloat16(acc[j][l * 16 + o]);
    }
    // stats: sum / sumsq per channel over both positions
    const int lane = tid & 63;
    for (int k = 0; k < 48; k++) {
        float sv = wave_sum(acc[0][k] + acc[1][k]);
        float qv = wave_sum(acc[0][k] * acc[0][k] + acc[1][k] * acc[1][k]);
        if (lane == 0) { atomicAdd(&bins[k], sv); atomicAdd(&bins[48 + k], qv); }
    }
    __syncthreads();
    if (tid < 96) atomicAdd(&st[tid], bins[tid]);
}

// ---- K2: finalize down affines (48 channels)
__global__ __launch_bounds__(64) void k_findown(
    const float* __restrict__ st, const float* __restrict__ gd,
    const float* __restrict__ betad, float* __restrict__ AC)
{
    int t = threadIdx.x;
    if (t < 48) {
        float m   = st[t] * (1.f / CNTF);
        float var = st[48 + t] * (1.f / CNTF) - m * m;
        float a   = gd[t] * rsqrtf(var + EPS);
        AC[t]      = a;
        AC[48 + t] = betad[t] - a * m;
    }
}

// ---- K3: per-layer z = Wsub . (xd_relu) mixed by PA; z bf16 out + sub BN stats
// 320 threads (5 waves), 8 nt per block, thread <-> (pp, ch=s*16+o), 2 pairs/thread
__global__ __launch_bounds__(320) void k_z(
    const __hip_bfloat16* __restrict__ xd, const float* __restrict__ PAl,
    const float* __restrict__ Wsl, const float* __restrict__ Al,
    const float* __restrict__ Cl, __hip_bfloat16* __restrict__ zbuf,
    float* __restrict__ stql)
{
    __shared__ float PAs[3500];       // [s][v][u pad 28]
    __shared__ float xds[3616];       // [8][452]: c*28+u
    __shared__ float bins[160];
    __shared__ float As[16], Cs[16];
    const int tid = threadIdx.x;
    for (int i = tid; i < 3500; i += 320) {
        int s = i / 700, r = i - s * 700;
        int v = r / 28, u = r - v * 28;
        PAs[i] = (u < 25) ? PAl[(s * 25 + v) * 25 + u] : 0.f;
    }
    for (int i = tid; i < 3616; i += 320) xds[i] = 0.f;
    if (tid < 160) bins[tid] = 0.f;
    if (tid < 16) { As[tid] = Al[tid]; Cs[tid] = Cl[tid]; }
    __syncthreads();

    const int nt0 = blockIdx.x * 8;
    for (int i = tid; i < 3200; i += 320) {
        int lp = i / 400, r = i - lp * 400;
        int c = r / 25, u = r - c * 25;
        float xv = __bfloat162float(xd[(size_t)(nt0 + lp) * 400 + r]);
        xds[lp * 452 + c * 28 + u] = fmaxf(As[c] * xv + Cs[c], 0.f);
    }
    __syncthreads();

    const int pp = tid / 80, ch = tid - pp * 80;
    const int s = ch >> 4;
    float W[16];
#pragma unroll
    for (int c = 0; c < 16; c++) W[c] = Wsl[ch * 16 + c];

    float sacc = 0.f, qacc = 0.f;
    for (int pq = pp; pq < 8; pq += 4) {
        float e[28];
#pragma unroll
        for (int u = 0; u < 28; u++) e[u] = 0.f;
#pragma unroll
        for (int c = 0; c < 16; c++) {
            const float wc = W[c];
            const float* xr = &xds[pq * 452 + c * 28];
#pragma unroll
            for (int u4 = 0; u4 < 7; u4++) {
                const float4 xc = *(const float4*)&xr[u4 * 4];
                e[4*u4+0] += wc * xc.x; e[4*u4+1] += wc * xc.y;
                e[4*u4+2] += wc * xc.z; e[4*u4+3] += wc * xc.w;
            }
        }
        const size_t zb = (size_t)(nt0 + pq) * 2000 + ch;
        for (int v = 0; v < 25; v++) {
            float z = 0.f;
#pragma unroll
            for (int u4 = 0; u4 < 7; u4++) {
                const float4 pa = *(const float4*)&PAs[s * 700 + v * 28 + u4 * 4];
                z += pa.x*e[4*u4] + pa.y*e[4*u4+1] + pa.z*e[4*u4+2] + pa.w*e[4*u4+3];
            }
            sacc += z; qacc += z * z;
            zbuf[zb + v * 80] = __float2bfloat16(z);
        }
    }
    atomicAdd(&bins[ch], sacc);
    atomicAdd(&bins[80 + ch], qacc);
    __syncthreads();
    if (tid < 160) atomicAdd(&stql[tid], bins[tid]);
}

// ---- K4: per-layer apply affine + subset-0 add, RMW acc in d_out; stats on last
template <int FIRST, int LAST>
__global__ __launch_bounds__(256) void k_apply(
    const __hip_bfloat16* __restrict__ zbuf, const float* __restrict__ stql,
    const float* __restrict__ gsl, const float* __restrict__ betal,
    float* __restrict__ out, float* __restrict__ stout)
{
    __shared__ float AS[80], CS[80];
    __shared__ float tile[32][208];
    const int tid = threadIdx.x;
    if (tid < 80) {
        float m   = stql[tid] * (1.f / CNTF);
        float var = stql[80 + tid] * (1.f / CNTF) - m * m;
        float a   = gsl[tid] * rsqrtf(var + EPS);
        AS[tid] = a; CS[tid] = betal[tid] - a * m;
    }
    __syncthreads();

    const int nt0 = blockIdx.x * 8, n = nt0 >> 7, t0 = nt0 & 127;
    float outacc[64];
    if (tid < 200) {
        const int pp = tid / 25, v = tid - pp * 25;
        const uint4* z8 = (const uint4*)(zbuf + (size_t)(nt0 + pp) * 2000 + v * 80);
        float zb0[16];
#pragma unroll
        for (int j = 0; j < 2; j++) {
            uint4 w = z8[j];
            zb0[j*8+0] = AS[j*8+0]*bfu(w.x & 0xffffu) + CS[j*8+0];
            zb0[j*8+1] = AS[j*8+1]*bfu(w.x >> 16)     + CS[j*8+1];
            zb0[j*8+2] = AS[j*8+2]*bfu(w.y & 0xffffu) + CS[j*8+2];
            zb0[j*8+3] = AS[j*8+3]*bfu(w.y >> 16)     + CS[j*8+3];
            zb0[j*8+4] = AS[j*8+4]*bfu(w.z & 0xffffu) + CS[j*8+4];
            zb0[j*8+5] = AS[j*8+5]*bfu(w.z >> 16)     + CS[j*8+5];
            zb0[j*8+6] = AS[j*8+6]*bfu(w.w & 0xffffu) + CS[j*8+6];
            zb0[j*8+7] = AS[j*8+7]*bfu(w.w >> 16)     + CS[j*8+7];
        }
#pragma unroll
        for (int j = 2; j < 10; j++) {
            uint4 w = z8[j];
            const int k = j * 8 - 16;
            outacc[k+0] = AS[16+k+0]*bfu(w.x & 0xffffu) + CS[16+k+0] + zb0[(k+0)&15];
            outacc[k+1] = AS[16+k+1]*bfu(w.x >> 16)     + CS[16+k+1] + zb0[(k+1)&15];
            outacc[k+2] = AS[16+k+2]*bfu(w.y & 0xffffu) + CS[16+k+2] + zb0[(k+2)&15];
            outacc[k+3] = AS[16+k+3]*bfu(w.y >> 16)     + CS[16+k+3] + zb0[(k+3)&15];
            outacc[k+4] = AS[16+k+4]*bfu(w.z & 0xffffu) + CS[16+k+4] + zb0[(k+4)&15];
            outacc[k+5] = AS[16+k+5]*bfu(w.z >> 16)     + CS[16+k+5] + zb0[(k+5)&15];
            outacc[k+6] = AS[16+k+6]*bfu(w.w & 0xffffu) + CS[16+k+6] + zb0[(k+6)&15];
            outacc[k+7] = AS[16+k+7]*bfu(w.w >> 16)     + CS[16+k+7] + zb0[(k+7)&15];
        }
    }
#pragma unroll
    for (int h = 0; h < 2; h++) {
        __syncthreads();
        if (tid < 200) {
#pragma unroll
            for (int kk = 0; kk < 32; kk++) tile[kk][tid] = outacc[h * 32 + kk];
        }
        __syncthreads();
        for (int i = tid; i < 6400; i += 256) {
            int kk = i / 200, p = i - kk * 200;
            int adr = n * 204800 + (h * 32 + kk) * 3200 + t0 * 25 + p;
            float val = tile[kk][p] + (FIRST ? 0.f : out[adr]);
            out[adr] = val;
            if (LAST) tile[kk][p] = val;
        }
        if (LAST) {
            __syncthreads();
            int kk = tid >> 3, c8 = tid & 7;
            float sv = 0.f, qv = 0.f;
            for (int j = 0; j < 25; j++) {
                float xv = tile[kk][c8 * 25 + j];
                sv += xv; qv += xv * xv;
            }
            sv += __shfl_down(sv, 4, 8); sv += __shfl_down(sv, 2, 8); sv += __shfl_down(sv, 1, 8);
            qv += __shfl_down(qv, 4, 8); qv += __shfl_down(qv, 2, 8); qv += __shfl_down(qv, 1, 8);
            if ((tid & 7) == 0) {
                atomicAdd(&stout[h * 32 + kk], sv);
                atomicAdd(&stout[64 + h * 32 + kk], qv);
            }
        }
    }
}

// ---- K5: out = relu(bn(acc) + x), in place on d_out
__global__ __launch_bounds__(256) void k_final(
    const float* __restrict__ x, const float* __restrict__ go,
    const float* __restrict__ bo, const float* __restrict__ stout,
    float* __restrict__ out)
{
    __shared__ float ao[64], co[64];
    const int tid = threadIdx.x;
    if (tid < 64) {
        float m   = stout[tid] * (1.f / CNTF);
        float var = stout[64 + tid] * (1.f / CNTF) - m * m;
        float a   = go[tid] * rsqrtf(var + EPS);
        ao[tid] = a; co[tid] = bo[tid] - m * a;
    }
    __syncthreads();
    const float4* x4 = (const float4*)x;
    float4* o4 = (float4*)out;
    for (int i = blockIdx.x * 256 + tid; i < 6553600; i += gridDim.x * 256) {
        int k = (i / 800) & 63;
        float a = ao[k], c = co[k];
        float4 vo = o4[i], vx = x4[i];
        vo.x = fmaxf(fmaf(a, vo.x, c) + vx.x, 0.f);
        vo.y = fmaxf(fmaf(a, vo.y, c) + vx.y, 0.f);
        vo.z = fmaxf(fmaf(a, vo.z, c) + vx.z, 0.f);
        vo.w = fmaxf(fmaf(a, vo.w, c) + vx.w, 0.f);
        o4[i] = vo;
    }
}

extern "C" void kernel_launch(void* const* d_in, const int* in_sizes, int n_in,
                              void* d_out, int out_size, void* d_ws, size_t ws_size,
                              hipStream_t stream)
{
    const float* x     = (const float*)d_in[0];
    const float* PA    = (const float*)d_in[1];
    const float* Wd    = (const float*)d_in[2];
    const float* gd    = (const float*)d_in[4];
    const float* betad = (const float*)d_in[5];
    const float* Wsub  = (const float*)d_in[6];
    const float* gsub  = (const float*)d_in[8];
    const float* betas = (const float*)d_in[9];
    const float* gout  = (const float*)d_in[10];
    const float* betao = (const float*)d_in[11];
    float* out = (float*)d_out;

    __hip_bfloat16* xdp  = (__hip_bfloat16*)d_ws;                  // 3*6.55M bf16 = 39.3 MB
    __hip_bfloat16* zbuf = xdp + (size_t)3 * XDP_ELEMS;            // 32.77M bf16 = 65.5 MB (per-layer reuse)
    float* st    = (float*)(zbuf + (size_t)Z_ELEMS);
    float* AC    = st + 96;
    float* stq   = AC + 96;       // [3][160]
    float* stout = stq + 480;     // [128]

    hipMemsetAsync(st, 0, 800 * sizeof(float), stream);

    k_down3  <<<800, 256, 0, stream>>>(x, Wd, xdp, st);
    k_findown<<<1,    64, 0, stream>>>(st, gd, betad, AC);

    for (int l = 0; l < 3; l++) {
        k_z<<<2048, 320, 0, stream>>>(xdp + (size_t)l * XDP_ELEMS, PA + l * 3125,
                                      Wsub + l * 1280, AC + l * 16, AC + 48 + l * 16,
                                      zbuf, stq + l * 160);
        if (l == 0)
            k_apply<1, 0><<<2048, 256, 0, stream>>>(zbuf, stq + l * 160, gsub + l * 80,
                                                    betas + l * 80, out, stout);
        else if (l == 1)
            k_apply<0, 0><<<2048, 256, 0, stream>>>(zbuf, stq + l * 160, gsub + l * 80,
                                                    betas + l * 80, out, stout);
        else
            k_apply<0, 1><<<2048, 256, 0, stream>>>(zbuf, stq + l * 160, gsub + l * 80,
                                                    betas + l * 80, out, stout);
    }
    k_final<<<2048, 256, 0, stream>>>(x, gout, betao, stout, out);
}

// Round 4
// 897.156 us; speedup vs baseline: 5.6583x; 5.6583x over previous
//
#include <hip/hip_runtime.h>

#define EPS  1e-5f
#define CNTF 409600.0f            // N*T*V
#define XDP_ELEMS 6553600         // per layer: 16384 nt * 400, layout [nt][u][16o]
#define Z_ELEMS   32768000        // 16384 * 2000, layout [nt][v][80ch]

__device__ __forceinline__ float wave_sum(float v) {
#pragma unroll
    for (int off = 32; off > 0; off >>= 1)
        v += __shfl_down(v, off, 64);
    return v;
}

__device__ __forceinline__ float bfu(unsigned int u16) {
    union { unsigned int i; float f; } x;
    x.i = u16 << 16;
    return x.f;
}
__device__ __forceinline__ unsigned int f2bf(float f) {
    union { float f; unsigned int i; } u; u.f = f;
    unsigned int r = u.i + 0x7fff + ((u.i >> 16) & 1);
    return r >> 16;
}

// ---- K1: conv_down all 3 layers (bias cancels in BN), bf16 xd + stats
// xdp layout: [l][p=nt*25+u][16 o]  -> 32B contiguous per (lane,layer)
__global__ __launch_bounds__(256) void k_down3(
    const float* __restrict__ x, const float* __restrict__ Wd,
    unsigned short* __restrict__ xdp, float* __restrict__ st /*96*/)
{
    __shared__ float Wt[64][48];
    __shared__ float bins[96];
    const int tid = threadIdx.x;
    for (int i = tid; i < 3072; i += 256) {
        int c = i / 48, k = i - c * 48;
        int l = k / 16, o = k - l * 16;
        Wt[c][k] = Wd[l * 1024 + o * 64 + c];
    }
    if (tid < 96) bins[tid] = 0.f;
    __syncthreads();

    const int base = (blockIdx.x * 256 + tid) * 2;
    const int n = base / 3200, pb = base - n * 3200;
    const float* xb = x + n * 204800 + pb;
    float acc[2][48];
#pragma unroll
    for (int k = 0; k < 48; k++) { acc[0][k] = 0.f; acc[1][k] = 0.f; }
    for (int c = 0; c < 64; c++) {
        float2 xv = *(const float2*)&xb[c * 3200];
#pragma unroll
        for (int k = 0; k < 48; k++) {
            float wv = Wt[c][k];
            acc[0][k] += wv * xv.x;
            acc[1][k] += wv * xv.y;
        }
    }
#pragma unroll
    for (int l = 0; l < 3; l++)
#pragma unroll
        for (int j = 0; j < 2; j++) {
            unsigned int pk[8];
#pragma unroll
            for (int h = 0; h < 8; h++)
                pk[h] = f2bf(acc[j][l*16 + 2*h]) | (f2bf(acc[j][l*16 + 2*h + 1]) << 16);
            uint4* dst = (uint4*)(xdp + (size_t)l * XDP_ELEMS + (size_t)(base + j) * 16);
            dst[0] = make_uint4(pk[0], pk[1], pk[2], pk[3]);
            dst[1] = make_uint4(pk[4], pk[5], pk[6], pk[7]);
        }

    const int lane = tid & 63;
    for (int k = 0; k < 48; k++) {
        float sv = wave_sum(acc[0][k] + acc[1][k]);
        float qv = wave_sum(acc[0][k] * acc[0][k] + acc[1][k] * acc[1][k]);
        if (lane == 0) { atomicAdd(&bins[k], sv); atomicAdd(&bins[48 + k], qv); }
    }
    __syncthreads();
    if (tid < 96) atomicAdd(&st[tid], bins[tid]);
}

// ---- K2: finalize down affines
__global__ __launch_bounds__(64) void k_findown(
    const float* __restrict__ st, const float* __restrict__ gd,
    const float* __restrict__ betad, float* __restrict__ AC)
{
    int t = threadIdx.x;
    if (t < 48) {
        float m   = st[t] * (1.f / CNTF);
        float var = st[48 + t] * (1.f / CNTF) - m * m;
        float a   = gd[t] * rsqrtf(var + EPS);
        AC[t]      = a;
        AC[48 + t] = betad[t] - a * m;
    }
}

// ---- K3: per-layer z + sub BN stats; z staged in LDS, flushed coalesced.
// 320 thr, 4 nt/block, thread <-> (pp=tid/80, ch=tid%80)
__global__ __launch_bounds__(320) void k_z(
    const unsigned short* __restrict__ xd, const float* __restrict__ PAl,
    const float* __restrict__ Wsl, const float* __restrict__ Al,
    const float* __restrict__ Cl, unsigned short* __restrict__ zbuf,
    float* __restrict__ stql)
{
    __shared__ float PAs[3500];             // [s][v][u pad28]
    __shared__ float xds[4][25][16];        // [pp][u][c]
    __shared__ unsigned short ztile[4][2000];  // [pp][v*80+ch]
    __shared__ float bins[160];
    __shared__ float As[16], Cs[16];
    const int tid = threadIdx.x;
    for (int i = tid; i < 3500; i += 320) {
        int s = i / 700, r = i - s * 700;
        int v = r / 28, u = r - v * 28;
        PAs[i] = (u < 25) ? PAl[(s * 25 + v) * 25 + u] : 0.f;
    }
    if (tid < 160) bins[tid] = 0.f;
    if (tid < 16) { As[tid] = Al[tid]; Cs[tid] = Cl[tid]; }
    __syncthreads();

    const int nt0 = blockIdx.x * 4;
    if (tid < 200) {
        int pp = tid / 50, r = tid - pp * 50;
        int u = r >> 1, half = r & 1;
        const uint4 w = *(const uint4*)(xd + (size_t)(nt0 + pp) * 400 + u * 16 + half * 8);
        float* dst = &xds[pp][u][half * 8];
        const float* A = &As[half * 8];
        const float* C = &Cs[half * 8];
        dst[0] = fmaxf(A[0] * bfu(w.x & 0xffffu) + C[0], 0.f);
        dst[1] = fmaxf(A[1] * bfu(w.x >> 16)     + C[1], 0.f);
        dst[2] = fmaxf(A[2] * bfu(w.y & 0xffffu) + C[2], 0.f);
        dst[3] = fmaxf(A[3] * bfu(w.y >> 16)     + C[3], 0.f);
        dst[4] = fmaxf(A[4] * bfu(w.z & 0xffffu) + C[4], 0.f);
        dst[5] = fmaxf(A[5] * bfu(w.z >> 16)     + C[5], 0.f);
        dst[6] = fmaxf(A[6] * bfu(w.w & 0xffffu) + C[6], 0.f);
        dst[7] = fmaxf(A[7] * bfu(w.w >> 16)     + C[7], 0.f);
    }
    __syncthreads();

    const int pp = tid / 80, ch = tid - pp * 80;
    const int s = ch >> 4;
    float W[16];
#pragma unroll
    for (int c = 0; c < 16; c++) W[c] = Wsl[ch * 16 + c];

    float e[28];
    e[25] = 0.f; e[26] = 0.f; e[27] = 0.f;
#pragma unroll
    for (int u = 0; u < 25; u++) {
        const float* xr = xds[pp][u];
        float4 a0 = *(const float4*)&xr[0];
        float4 a1 = *(const float4*)&xr[4];
        float4 a2 = *(const float4*)&xr[8];
        float4 a3 = *(const float4*)&xr[12];
        e[u] = W[0]*a0.x + W[1]*a0.y + W[2]*a0.z + W[3]*a0.w
             + W[4]*a1.x + W[5]*a1.y + W[6]*a1.z + W[7]*a1.w
             + W[8]*a2.x + W[9]*a2.y + W[10]*a2.z + W[11]*a2.w
             + W[12]*a3.x + W[13]*a3.y + W[14]*a3.z + W[15]*a3.w;
    }
    float sacc = 0.f, qacc = 0.f;
    unsigned short* zt = &ztile[pp][ch];
    for (int v = 0; v < 25; v++) {
        float z = 0.f;
#pragma unroll
        for (int u4 = 0; u4 < 7; u4++) {
            const float4 pa = *(const float4*)&PAs[s * 700 + v * 28 + u4 * 4];
            z += pa.x*e[4*u4] + pa.y*e[4*u4+1] + pa.z*e[4*u4+2] + pa.w*e[4*u4+3];
        }
        sacc += z; qacc += z * z;
        zt[v * 80] = (unsigned short)f2bf(z);
    }
    atomicAdd(&bins[ch], sacc);
    atomicAdd(&bins[80 + ch], qacc);
    __syncthreads();
    if (tid < 160) atomicAdd(&stql[tid], bins[tid]);

    // coalesced flush: 4 nt * 2000 ushort = 1000 uint4, contiguous 16KB
    const uint4* zt4 = (const uint4*)ztile;
    uint4* dst = (uint4*)(zbuf + (size_t)nt0 * 2000);
    for (int i = tid; i < 1000; i += 320) dst[i] = zt4[i];
}

// ---- K4: apply affine + subset-0 add, RMW acc in d_out; stats on last layer
template <int FIRST, int LAST>
__global__ __launch_bounds__(256) void k_apply(
    const unsigned short* __restrict__ zbuf, const float* __restrict__ stql,
    const float* __restrict__ gsl, const float* __restrict__ betal,
    float* __restrict__ out, float* __restrict__ stout)
{
    __shared__ float AS[80], CS[80];
    __shared__ float tile[32][208];
    const int tid = threadIdx.x;
    if (tid < 80) {
        float m   = stql[tid] * (1.f / CNTF);
        float var = stql[80 + tid] * (1.f / CNTF) - m * m;
        float a   = gsl[tid] * rsqrtf(var + EPS);
        AS[tid] = a; CS[tid] = betal[tid] - a * m;
    }
    __syncthreads();

    const int nt0 = blockIdx.x * 8, n = nt0 >> 7, t0 = nt0 & 127;
    float outacc[64];
    if (tid < 200) {
        const int pp = tid / 25, v = tid - pp * 25;
        const uint4* z8 = (const uint4*)(zbuf + (size_t)(nt0 + pp) * 2000 + v * 80);
        float zb0[16];
#pragma unroll
        for (int j = 0; j < 2; j++) {
            uint4 w = z8[j];
            zb0[j*8+0] = AS[j*8+0]*bfu(w.x & 0xffffu) + CS[j*8+0];
            zb0[j*8+1] = AS[j*8+1]*bfu(w.x >> 16)     + CS[j*8+1];
            zb0[j*8+2] = AS[j*8+2]*bfu(w.y & 0xffffu) + CS[j*8+2];
            zb0[j*8+3] = AS[j*8+3]*bfu(w.y >> 16)     + CS[j*8+3];
            zb0[j*8+4] = AS[j*8+4]*bfu(w.z & 0xffffu) + CS[j*8+4];
            zb0[j*8+5] = AS[j*8+5]*bfu(w.z >> 16)     + CS[j*8+5];
            zb0[j*8+6] = AS[j*8+6]*bfu(w.w & 0xffffu) + CS[j*8+6];
            zb0[j*8+7] = AS[j*8+7]*bfu(w.w >> 16)     + CS[j*8+7];
        }
#pragma unroll
        for (int j = 2; j < 10; j++) {
            uint4 w = z8[j];
            const int k = j * 8 - 16;
            outacc[k+0] = AS[16+k+0]*bfu(w.x & 0xffffu) + CS[16+k+0] + zb0[(k+0)&15];
            outacc[k+1] = AS[16+k+1]*bfu(w.x >> 16)     + CS[16+k+1] + zb0[(k+1)&15];
            outacc[k+2] = AS[16+k+2]*bfu(w.y & 0xffffu) + CS[16+k+2] + zb0[(k+2)&15];
            outacc[k+3] = AS[16+k+3]*bfu(w.y >> 16)     + CS[16+k+3] + zb0[(k+3)&15];
            outacc[k+4] = AS[16+k+4]*bfu(w.z & 0xffffu) + CS[16+k+4] + zb0[(k+4)&15];
            outacc[k+5] = AS[16+k+5]*bfu(w.z >> 16)     + CS[16+k+5] + zb0[(k+5)&15];
            outacc[k+6] = AS[16+k+6]*bfu(w.w & 0xffffu) + CS[16+k+6] + zb0[(k+6)&15];
            outacc[k+7] = AS[16+k+7]*bfu(w.w >> 16)     + CS[16+k+7] + zb0[(k+7)&15];
        }
    }
#pragma unroll
    for (int h = 0; h < 2; h++) {
        __syncthreads();
        if (tid < 200) {
#pragma unroll
            for (int kk = 0; kk < 32; kk++) tile[kk][tid] = outacc[h * 32 + kk];
        }
        __syncthreads();
        for (int i = tid; i < 6400; i += 256) {
            int kk = i / 200, p = i - kk * 200;
            int adr = n * 204800 + (h * 32 + kk) * 3200 + t0 * 25 + p;
            float val = tile[kk][p] + (FIRST ? 0.f : out[adr]);
            out[adr] = val;
            if (LAST) tile[kk][p] = val;
        }
        if (LAST) {
            __syncthreads();
            int kk = tid >> 3, c8 = tid & 7;
            float sv = 0.f, qv = 0.f;
            for (int j = 0; j < 25; j++) {
                float xv = tile[kk][c8 * 25 + j];
                sv += xv; qv += xv * xv;
            }
            sv += __shfl_down(sv, 4, 8); sv += __shfl_down(sv, 2, 8); sv += __shfl_down(sv, 1, 8);
            qv += __shfl_down(qv, 4, 8); qv += __shfl_down(qv, 2, 8); qv += __shfl_down(qv, 1, 8);
            if ((tid & 7) == 0) {
                atomicAdd(&stout[h * 32 + kk], sv);
                atomicAdd(&stout[64 + h * 32 + kk], qv);
            }
        }
    }
}

// ---- K5: out = relu(bn(acc) + x), in place on d_out
__global__ __launch_bounds__(256) void k_final(
    const float* __restrict__ x, const float* __restrict__ go,
    const float* __restrict__ bo, const float* __restrict__ stout,
    float* __restrict__ out)
{
    __shared__ float ao[64], co[64];
    const int tid = threadIdx.x;
    if (tid < 64) {
        float m   = stout[tid] * (1.f / CNTF);
        float var = stout[64 + tid] * (1.f / CNTF) - m * m;
        float a   = go[tid] * rsqrtf(var + EPS);
        ao[tid] = a; co[tid] = bo[tid] - m * a;
    }
    __syncthreads();
    const float4* x4 = (const float4*)x;
    float4* o4 = (float4*)out;
    for (int i = blockIdx.x * 256 + tid; i < 6553600; i += gridDim.x * 256) {
        int k = (i / 800) & 63;
        float a = ao[k], c = co[k];
        float4 vo = o4[i], vx = x4[i];
        vo.x = fmaxf(fmaf(a, vo.x, c) + vx.x, 0.f);
        vo.y = fmaxf(fmaf(a, vo.y, c) + vx.y, 0.f);
        vo.z = fmaxf(fmaf(a, vo.z, c) + vx.z, 0.f);
        vo.w = fmaxf(fmaf(a, vo.w, c) + vx.w, 0.f);
        o4[i] = vo;
    }
}

extern "C" void kernel_launch(void* const* d_in, const int* in_sizes, int n_in,
                              void* d_out, int out_size, void* d_ws, size_t ws_size,
                              hipStream_t stream)
{
    const float* x     = (const float*)d_in[0];
    const float* PA    = (const float*)d_in[1];
    const float* Wd    = (const float*)d_in[2];
    const float* gd    = (const float*)d_in[4];
    const float* betad = (const float*)d_in[5];
    const float* Wsub  = (const float*)d_in[6];
    const float* gsub  = (const float*)d_in[8];
    const float* betas = (const float*)d_in[9];
    const float* gout  = (const float*)d_in[10];
    const float* betao = (const float*)d_in[11];
    float* out = (float*)d_out;

    unsigned short* xdp  = (unsigned short*)d_ws;            // 3 * 6.5536M * 2B = 39.3 MB
    unsigned short* zbuf = xdp + (size_t)3 * XDP_ELEMS;      // 65.5 MB, reused per layer
    float* st    = (float*)(zbuf + (size_t)Z_ELEMS);
    float* AC    = st + 96;
    float* stq   = AC + 96;       // [3][160]
    float* stout = stq + 480;     // [128]

    hipMemsetAsync(st, 0, 800 * sizeof(float), stream);

    k_down3  <<<800, 256, 0, stream>>>(x, Wd, xdp, st);
    k_findown<<<1,    64, 0, stream>>>(st, gd, betad, AC);

    for (int l = 0; l < 3; l++) {
        k_z<<<4096, 320, 0, stream>>>(xdp + (size_t)l * XDP_ELEMS, PA + l * 3125,
                                      Wsub + l * 1280, AC + l * 16, AC + 48 + l * 16,
                                      zbuf, stq + l * 160);
        if (l == 0)
            k_apply<1, 0><<<2048, 256, 0, stream>>>(zbuf, stq + l * 160, gsub + l * 80,
                                                    betas + l * 80, out, stout);
        else if (l == 1)
            k_apply<0, 0><<<2048, 256, 0, stream>>>(zbuf, stq + l * 160, gsub + l * 80,
                                                    betas + l * 80, out, stout);
        else
            k_apply<0, 1><<<2048, 256, 0, stream>>>(zbuf, stq + l * 160, gsub + l * 80,
                                                    betas + l * 80, out, stout);
    }
    k_final<<<2048, 256, 0, stream>>>(x, gout, betao, stout, out);
}